// Round 5
// baseline (463.831 us; speedup 1.0000x reference)
//
#include <hip/hip_runtime.h>
#include <cstdint>

// Problem: B=8, LQ=LK=2048, DIM=128.
// out  [B,LQ,DIM] f32 = softmax(mask? -inf : QK^T/sqrt(D)) @ K
// attn [B,LQ,LK]  f32 = log_softmax(...)  (clamp logp to -1e30)
//
// R9: R8 (reg-prefetch, barrier-free) gave 114->91us but stalled at 2
//     waves/SIMD (occupancy 17.9%, all pipes <27%). This round keeps R8's
//     verified loop body and doubles concurrency:
//     - 512-thr blocks, 8 waves x 256-col strips -> 16 waves/CU (4/SIMD).
//     - mask pre-packed to 2x u64 bits/lane in prologue: zero mask loads in
//       BOTH hot loops (removes the L3-latency the 1-deep prefetch missed),
//       mask HBM traffic halved.
//     - 8-strip merge; PV merge in 2 parallel LDS buffers (4 rounds).

#define DIMV 128
constexpr int BB = 8;
constexpr int LQ = 2048;
constexpr int LK = 2048;
constexpr float QSCALE = 0.08838834764831843f; // 1/sqrt(128), folded into Q

typedef _Float16 half8 __attribute__((ext_vector_type(8)));
typedef _Float16 half4v __attribute__((ext_vector_type(4)));
typedef float float4v __attribute__((ext_vector_type(4)));

// ---- prep: build fragment-major Qf, Kf, Vf (fp16) in ws ---- (verified R7/R8)
// Qf/Kf[b]: [tile(128)][kk(4)][lane(64)][8]  elem [t*16+l16][kk*32+quad*8+e]
// Vf[b]:    [kt(128)][dp(4)][lane(64)][8]    elem e<4:  V[kt*16+quad*4+e][(2dp)*16+l16]
//                                            elem e>=4: V[kt*16+quad*4+e-4][(2dp+1)*16+l16]
__global__ __launch_bounds__(256) void prep_kernel(const float* __restrict__ q,
                                                   const float* __restrict__ ctx,
                                                   _Float16* __restrict__ Qf,
                                                   _Float16* __restrict__ Kf,
                                                   _Float16* __restrict__ Vf) {
    __shared__ float tile[32][132];
    const int tid  = threadIdx.x;
    const int mode = blockIdx.x >> 9;     // 0:Qf 1:Kf 2:Vf
    const int t    = blockIdx.x & 511;
    const int b    = t >> 6;
    const int r0   = (t & 63) * 32;       // 32 rows of 2048
    const float4* s4 = (const float4*)((mode == 0 ? q : ctx) + ((size_t)b * 2048 + r0) * DIMV);
    for (int v = 0; v < 4; v++) {
        int off = tid + v * 256;
        float4 f = s4[off];
        int row = off >> 5, c4 = (off & 31) * 4;
        tile[row][c4 + 0] = f.x; tile[row][c4 + 1] = f.y;
        tile[row][c4 + 2] = f.z; tile[row][c4 + 3] = f.w;
    }
    __syncthreads();
    if (mode < 2) {
        const float qs = (mode == 0) ? QSCALE : 1.0f;
        _Float16* dst = (mode == 0 ? Qf : Kf) + (size_t)b * (2048 * DIMV);
        for (int c = 0; c < 2; c++) {
            int chunk = tid + c * 256;                 // (t2, kk, lane)
            int t2 = chunk >> 8, kk = (chunk >> 6) & 3, lane = chunk & 63;
            int quad = lane >> 4, l16 = lane & 15;
            int r = t2 * 16 + l16, d0 = kk * 32 + quad * 8;
            half8 h;
            for (int e = 0; e < 8; e++) h[e] = (_Float16)(tile[r][d0 + e] * qs);
            size_t tl = (size_t)(r0 >> 4) + t2;
            *(half8*)(dst + ((tl * 4 + kk) * 64 + lane) * 8) = h;
        }
    } else {
        _Float16* dst = Vf + (size_t)b * (2048 * DIMV);
        const int kt0 = r0 >> 4;
        for (int c = 0; c < 2; c++) {
            int chunk = tid + c * 256;                 // (ktl, dp, lane)
            int ktl = chunk >> 8, dp = (chunk >> 6) & 3, ln = chunk & 63;
            int qd = ln >> 4, s16 = ln & 15;
            half8 h;
            for (int e = 0; e < 4; e++) {
                h[e]     = (_Float16)tile[ktl * 16 + qd * 4 + e][(2 * dp) * 16 + s16];
                h[e + 4] = (_Float16)tile[ktl * 16 + qd * 4 + e][(2 * dp + 1) * 16 + s16];
            }
            *(half8*)(dst + ((((size_t)(kt0 + ktl)) * 4 + dp) * 64 + ln) * 8) = h;
        }
    }
}

// ---- main fused kernel: one block = (batch, 32 q-rows), 8 waves, 2 blk/CU ----
// wave owns col-strip [wave*256, wave*256+256) = 16 tiles; 2 sub-blocks of 16 rows.
__global__ __launch_bounds__(512, 4)
void attn_kernel(const unsigned char* __restrict__ mask,
                 const _Float16* __restrict__ Qf, const _Float16* __restrict__ Kf,
                 const _Float16* __restrict__ Vf,
                 float* __restrict__ out, float* __restrict__ out_attn) {
    __shared__ __attribute__((aligned(16))) float pvsum[2][32][132];  // 33.8 KB
    __shared__ float redm[8][32], redl[8][32], swf[8][32];            //  3.0 KB
    __shared__ float mcl32[32], rls32[32];

    const int tid  = threadIdx.x;
    const int wave = tid >> 6;           // 0..7
    const int lane = tid & 63;
    const int l16  = lane & 15;
    const int quad = lane >> 4;

    const int b  = blockIdx.x & 7;       // XCD-aware batch mapping (batch b -> XCD b)
    const int qg = blockIdx.x >> 3;      // 0..63
    const int q0 = qg * 32;

    const _Float16* Qb = Qf + (size_t)b * (2048 * DIMV);
    const _Float16* Kb = Kf + (size_t)b * (2048 * DIMV);
    const _Float16* Vb = Vf + (size_t)b * (2048 * DIMV);

    // Q fragments (B-operand), pre-scaled: 2 sub-blocks of 16 rows
    half8 qfrag[2][4];
#pragma unroll
    for (int sub = 0; sub < 2; sub++) {
        const size_t tq = (size_t)qg * 2 + sub;
#pragma unroll
        for (int kk = 0; kk < 4; kk++)
            qfrag[sub][kk] = *(const half8*)(Qb + ((tq * 4 + kk) * 64 + lane) * 8);
    }

    // ---- prologue: pack this lane's mask bytes into 2x u64 (bit ct*4+r) ----
    // robust: bit = (byte != 0), via OR-fold of each byte's bits into its LSB
    const unsigned char* mrow0 = mask + ((size_t)b * LQ + q0 + l16) * LK + wave * 256 + quad * 4;
    uint64_t mpack[2];
#pragma unroll
    for (int sub = 0; sub < 2; sub++) {
        uint64_t pk = 0;
#pragma unroll
        for (int ct = 0; ct < 16; ct++) {
            uint32_t w = *(const uint32_t*)(mrow0 + (size_t)sub * 16 * LK + ct * 16);
            w |= w >> 4; w |= w >> 2; w |= w >> 1;   // LSB of each byte = nonzero
            uint32_t nib = (w & 1u) | ((w >> 7) & 2u) | ((w >> 14) & 4u) | ((w >> 21) & 8u);
            pk |= (uint64_t)nib << (ct * 4);
        }
        mpack[sub] = pk;
    }

    const _Float16* kstrip = Kb + (size_t)wave * 16 * 2048; // this wave's 16 k-tiles
    const _Float16* vstrip = Vb + (size_t)wave * 16 * 2048;

    const float NEGINF = -__builtin_inff();
    float m0r = -1e30f, m1r = -1e30f;   // finite sentinel (avoid inf-inf NaN)
    float l0r = 0.f, l1r = 0.f;
    float4v oacc[2][8];
#pragma unroll
    for (int sub = 0; sub < 2; sub++)
#pragma unroll
        for (int dt = 0; dt < 8; dt++) oacc[sub][dt] = (float4v){0.f, 0.f, 0.f, 0.f};

    // ---- register double-buffer prefetch state ----
    half8 kfb[2][4], vvb[2][4];
    {   // prologue: tile 0 -> buf 0
#pragma unroll
        for (int kk = 0; kk < 4; kk++) kfb[0][kk] = *(const half8*)(kstrip + (kk * 64 + lane) * 8);
#pragma unroll
        for (int dp = 0; dp < 4; dp++) vvb[0][dp] = *(const half8*)(vstrip + (dp * 64 + lane) * 8);
    }

    // ---- pass 1: 16 tiles of 16 cols, barrier-free, issue-ahead pipeline ----
#pragma unroll 2
    for (int ct = 0; ct < 16; ++ct) {
        const int cur = ct & 1, nxt = cur ^ 1;
        const int cn  = (ct + 1) & 15;           // ct=15 reloads tile 0 (harmless)
        {   // issue next-tile loads FIRST; one full iteration of latency slack
            const _Float16* kp = kstrip + (size_t)cn * 2048;
            const _Float16* vp = vstrip + (size_t)cn * 2048;
#pragma unroll
            for (int kk = 0; kk < 4; kk++) kfb[nxt][kk] = *(const half8*)(kp + (kk * 64 + lane) * 8);
#pragma unroll
            for (int dp = 0; dp < 4; dp++) vvb[nxt][dp] = *(const half8*)(vp + (dp * 64 + lane) * 8);
        }
        __builtin_amdgcn_sched_barrier(0);       // pin: loads stay at iteration top

#pragma unroll
        for (int sub = 0; sub < 2; sub++) {
            float4v st = (float4v){0.f, 0.f, 0.f, 0.f};
            __builtin_amdgcn_s_setprio(1);
#pragma unroll
            for (int kk = 0; kk < 4; kk++)
                st = __builtin_amdgcn_mfma_f32_16x16x32_f16(kfb[cur][kk], qfrag[sub][kk], st, 0, 0, 0);
            __builtin_amdgcn_s_setprio(0);
            const uint32_t mb = (uint32_t)(mpack[sub] >> (ct * 4)) & 0xFu;  // registers, no load
            float& m = sub ? m1r : m0r;
            float& l = sub ? l1r : l0r;
            float sv[4];
#pragma unroll
            for (int r = 0; r < 4; r++) {
                float v = st[r];
                if ((mb >> r) & 1u) v = NEGINF;
                sv[r] = v;
            }
            float tmax = fmaxf(fmaxf(sv[0], sv[1]), fmaxf(sv[2], sv[3]));
            tmax = fmaxf(tmax, __shfl_xor(tmax, 16));
            tmax = fmaxf(tmax, __shfl_xor(tmax, 32));
            const bool upd = tmax > m + 3.0f;    // defer-rescale: p bounded by e^3
            if (__any(upd)) {
                const float mnew = upd ? tmax : m;
                const float sc = __expf(m - mnew);
                float scr[4];
#pragma unroll
                for (int r = 0; r < 4; r++) scr[r] = __shfl(sc, quad * 4 + r);
                l *= sc;
#pragma unroll
                for (int dt = 0; dt < 8; dt++)
#pragma unroll
                    for (int r = 0; r < 4; r++) oacc[sub][dt][r] *= scr[r];
                m = mnew;
            }
            half4v pa;
            float pp[4];
#pragma unroll
            for (int r = 0; r < 4; r++) {
                pp[r] = __expf(sv[r] - m);       // masked: exp(-inf)=0
                pa[r] = (_Float16)pp[r];
            }
            // PV first (pa is the 16x16x16 A-operand directly)
            __builtin_amdgcn_s_setprio(1);
#pragma unroll
            for (int dp = 0; dp < 4; dp++) {
                half4v vlo = __builtin_shufflevector(vvb[cur][dp], vvb[cur][dp], 0, 1, 2, 3);
                half4v vhi = __builtin_shufflevector(vvb[cur][dp], vvb[cur][dp], 4, 5, 6, 7);
                oacc[sub][2 * dp]     = __builtin_amdgcn_mfma_f32_16x16x16f16(pa, vlo, oacc[sub][2 * dp],     0, 0, 0);
                oacc[sub][2 * dp + 1] = __builtin_amdgcn_mfma_f32_16x16x16f16(pa, vhi, oacc[sub][2 * dp + 1], 0, 0, 0);
            }
            __builtin_amdgcn_s_setprio(0);
            // l-update off the critical path (feeds nothing until the merge)
            float psum = (pp[0] + pp[1]) + (pp[2] + pp[3]);
            psum += __shfl_xor(psum, 16);
            psum += __shfl_xor(psum, 32);
            l += psum;
        }
    }

    // ---- merge stats across 8 col-strips ----
    if (quad == 0) {
        redm[wave][l16]      = m0r;  redm[wave][16 + l16] = m1r;
        redl[wave][l16]      = l0r;  redl[wave][16 + l16] = l1r;
    }
    // pass-2 prologue loads issued here: latency hidden under the merge barriers
    half8 kf2[2][4];
#pragma unroll
    for (int kk = 0; kk < 4; kk++) kf2[0][kk] = *(const half8*)(kstrip + (kk * 64 + lane) * 8);
    __syncthreads();
    if (tid < 32) {
        float mm[8], ll[8];
#pragma unroll
        for (int p = 0; p < 8; p++) { mm[p] = redm[p][tid]; ll[p] = redl[p][tid]; }
        float M = mm[0];
#pragma unroll
        for (int p = 1; p < 8; p++) M = fmaxf(M, mm[p]);
        float L = 0.f;
#pragma unroll
        for (int p = 0; p < 8; p++) {
            const float e = __expf(mm[p] - M);
            swf[p][tid] = e;
            L += e * ll[p];
        }
        mcl32[tid] = M + __logf(L);
        rls32[tid] = 1.0f / L;
    }
    __syncthreads();

    // ---- PV merge: waves 0-3 -> pvsum[0], waves 4-7 -> pvsum[1], 4 rounds ----
    for (int rnd = 0; rnd < 4; ++rnd) {
        if ((wave & 3) == rnd) {
            const int bf = wave >> 2;
#pragma unroll
            for (int sub = 0; sub < 2; sub++)
#pragma unroll
                for (int r = 0; r < 4; r++) {
                    const int row = sub * 16 + quad * 4 + r;
                    const float sc = swf[wave][row];
#pragma unroll
                    for (int dt = 0; dt < 8; dt++) {
                        const float v = oacc[sub][dt][r] * sc;
                        if (rnd == 0) pvsum[bf][row][dt * 16 + l16] = v;
                        else          pvsum[bf][row][dt * 16 + l16] += v;
                    }
                }
        }
        __syncthreads();
    }

    // ---- out = (pvsum[0]+pvsum[1]) / L, coalesced float4 ----
    {
        const int row = tid >> 4;
        const int c0  = (tid & 15) * 8;
        const float rcl = rls32[row];
        float* op = out + ((size_t)b * LQ + q0 + row) * DIMV + c0;
#pragma unroll
        for (int h = 0; h < 2; h++) {
            float4v a0 = *(const float4v*)&pvsum[0][row][c0 + h * 4];
            float4v a1 = *(const float4v*)&pvsum[1][row][c0 + h * 4];
            float4v v;
#pragma unroll
            for (int j = 0; j < 4; j++) v[j] = (a0[j] + a1[j]) * rcl;
            *(float4v*)(op + h * 4) = v;
        }
    }

    // ---- pass 2: recompute QK^T (K frags L2-hot), barrier-free, prefetched ----
    const float mc0 = mcl32[l16];
    const float mc1 = mcl32[16 + l16];
    float* oa0 = out_attn + ((size_t)b * LQ + q0 + l16) * LK + wave * 256 + quad * 4;
#pragma unroll 2
    for (int ct = 0; ct < 16; ++ct) {
        const int cur = ct & 1, nxt = cur ^ 1;
        const int cn  = (ct + 1) & 15;
        {
            const _Float16* kp = kstrip + (size_t)cn * 2048;
#pragma unroll
            for (int kk = 0; kk < 4; kk++) kf2[nxt][kk] = *(const half8*)(kp + (kk * 64 + lane) * 8);
        }
        __builtin_amdgcn_sched_barrier(0);

#pragma unroll
        for (int sub = 0; sub < 2; sub++) {
            float4v st = (float4v){0.f, 0.f, 0.f, 0.f};
            __builtin_amdgcn_s_setprio(1);
#pragma unroll
            for (int kk = 0; kk < 4; kk++)
                st = __builtin_amdgcn_mfma_f32_16x16x32_f16(kf2[cur][kk], qfrag[sub][kk], st, 0, 0, 0);
            __builtin_amdgcn_s_setprio(0);
            const uint32_t mb = (uint32_t)(mpack[sub] >> (ct * 4)) & 0xFu;
            const float mc = sub ? mc1 : mc0;
            float4v o;
#pragma unroll
            for (int r = 0; r < 4; r++) {
                float lp = st[r] - mc;
                if ((mb >> r) & 1u) lp = -1.0e30f;   // masked: finite sentinel
                o[r] = fmaxf(lp, -1.0e30f);
            }
            *(float4v*)(oa0 + (size_t)sub * 16 * LK + ct * 16) = o;
        }
    }
}

extern "C" void kernel_launch(void* const* d_in, const int* in_sizes, int n_in,
                              void* d_out, int out_size, void* d_ws, size_t ws_size,
                              hipStream_t stream) {
    const float* q_f32 = (const float*)d_in[0];
    const float* c_f32 = (const float*)d_in[1];
    const unsigned char* mask = (const unsigned char*)d_in[2];

    float* out      = (float*)d_out;
    float* out_attn = out + (size_t)BB * LQ * DIMV;

    _Float16* Qf = (_Float16*)d_ws;                    // 4.19 MB each
    _Float16* Kf = Qf + (size_t)BB * LQ * DIMV;
    _Float16* Vf = Kf + (size_t)BB * LK * DIMV;

    prep_kernel<<<1536, 256, 0, stream>>>(q_f32, c_f32, Qf, Kf, Vf);
    attn_kernel<<<BB * (LQ / 32), 512, 0, stream>>>(mask, Qf, Kf, Vf, out, out_attn);
}

// Round 6
// 282.394 us; speedup vs baseline: 1.6425x; 1.6425x over previous
//
#include <hip/hip_runtime.h>
#include <cstdint>

// Problem: B=8, LQ=LK=2048, DIM=128.
// out  [B,LQ,DIM] f32 = softmax(mask? -inf : QK^T/sqrt(D)) @ K
// attn [B,LQ,LK]  f32 = log_softmax(...)  (clamp logp to -1e30)
//
// R10: R9 regressed 91->292us from SCRATCH SPILLS: __launch_bounds__(512,4)
//      means min 4 BLOCKS/CU on this toolchain (CUDA semantics, confirmed by
//      VGPR_Count=64 = 8 waves/EU cap; FETCH/WRITE blew up to 590/560 MB of
//      spill traffic). Fix: (512,2) -> 2 blk/CU = 16 waves/CU, 128-VGPR cap
//      (R8 measured 108 live). Structure otherwise identical to R9:
//      8 waves x 256-col strips, reg double-buffer K/V prefetch, barrier-free
//      hot loops, in-register mask bitpack, dual-buffer PV merge.

#define DIMV 128
constexpr int BB = 8;
constexpr int LQ = 2048;
constexpr int LK = 2048;
constexpr float QSCALE = 0.08838834764831843f; // 1/sqrt(128), folded into Q

typedef _Float16 half8 __attribute__((ext_vector_type(8)));
typedef _Float16 half4v __attribute__((ext_vector_type(4)));
typedef float float4v __attribute__((ext_vector_type(4)));

// ---- prep: build fragment-major Qf, Kf, Vf (fp16) in ws ---- (verified R7/R8)
// Qf/Kf[b]: [tile(128)][kk(4)][lane(64)][8]  elem [t*16+l16][kk*32+quad*8+e]
// Vf[b]:    [kt(128)][dp(4)][lane(64)][8]    elem e<4:  V[kt*16+quad*4+e][(2dp)*16+l16]
//                                            elem e>=4: V[kt*16+quad*4+e-4][(2dp+1)*16+l16]
__global__ __launch_bounds__(256) void prep_kernel(const float* __restrict__ q,
                                                   const float* __restrict__ ctx,
                                                   _Float16* __restrict__ Qf,
                                                   _Float16* __restrict__ Kf,
                                                   _Float16* __restrict__ Vf) {
    __shared__ float tile[32][132];
    const int tid  = threadIdx.x;
    const int mode = blockIdx.x >> 9;     // 0:Qf 1:Kf 2:Vf
    const int t    = blockIdx.x & 511;
    const int b    = t >> 6;
    const int r0   = (t & 63) * 32;       // 32 rows of 2048
    const float4* s4 = (const float4*)((mode == 0 ? q : ctx) + ((size_t)b * 2048 + r0) * DIMV);
    for (int v = 0; v < 4; v++) {
        int off = tid + v * 256;
        float4 f = s4[off];
        int row = off >> 5, c4 = (off & 31) * 4;
        tile[row][c4 + 0] = f.x; tile[row][c4 + 1] = f.y;
        tile[row][c4 + 2] = f.z; tile[row][c4 + 3] = f.w;
    }
    __syncthreads();
    if (mode < 2) {
        const float qs = (mode == 0) ? QSCALE : 1.0f;
        _Float16* dst = (mode == 0 ? Qf : Kf) + (size_t)b * (2048 * DIMV);
        for (int c = 0; c < 2; c++) {
            int chunk = tid + c * 256;                 // (t2, kk, lane)
            int t2 = chunk >> 8, kk = (chunk >> 6) & 3, lane = chunk & 63;
            int quad = lane >> 4, l16 = lane & 15;
            int r = t2 * 16 + l16, d0 = kk * 32 + quad * 8;
            half8 h;
            for (int e = 0; e < 8; e++) h[e] = (_Float16)(tile[r][d0 + e] * qs);
            size_t tl = (size_t)(r0 >> 4) + t2;
            *(half8*)(dst + ((tl * 4 + kk) * 64 + lane) * 8) = h;
        }
    } else {
        _Float16* dst = Vf + (size_t)b * (2048 * DIMV);
        const int kt0 = r0 >> 4;
        for (int c = 0; c < 2; c++) {
            int chunk = tid + c * 256;                 // (ktl, dp, lane)
            int ktl = chunk >> 8, dp = (chunk >> 6) & 3, ln = chunk & 63;
            int qd = ln >> 4, s16 = ln & 15;
            half8 h;
            for (int e = 0; e < 4; e++) {
                h[e]     = (_Float16)tile[ktl * 16 + qd * 4 + e][(2 * dp) * 16 + s16];
                h[e + 4] = (_Float16)tile[ktl * 16 + qd * 4 + e][(2 * dp + 1) * 16 + s16];
            }
            *(half8*)(dst + ((((size_t)(kt0 + ktl)) * 4 + dp) * 64 + ln) * 8) = h;
        }
    }
}

// ---- main fused kernel: one block = (batch, 32 q-rows), 8 waves, 2 blk/CU ----
// wave owns col-strip [wave*256, wave*256+256) = 16 tiles; 2 sub-blocks of 16 rows.
__global__ __launch_bounds__(512, 2)   // 2 BLOCKS/CU (CUDA semantics) -> 128 VGPR cap
void attn_kernel(const unsigned char* __restrict__ mask,
                 const _Float16* __restrict__ Qf, const _Float16* __restrict__ Kf,
                 const _Float16* __restrict__ Vf,
                 float* __restrict__ out, float* __restrict__ out_attn) {
    __shared__ __attribute__((aligned(16))) float pvsum[2][32][132];  // 33.8 KB
    __shared__ float redm[8][32], redl[8][32], swf[8][32];            //  3.0 KB
    __shared__ float mcl32[32], rls32[32];

    const int tid  = threadIdx.x;
    const int wave = tid >> 6;           // 0..7
    const int lane = tid & 63;
    const int l16  = lane & 15;
    const int quad = lane >> 4;

    const int b  = blockIdx.x & 7;       // XCD-aware batch mapping (batch b -> XCD b)
    const int qg = blockIdx.x >> 3;      // 0..63
    const int q0 = qg * 32;

    const _Float16* Qb = Qf + (size_t)b * (2048 * DIMV);
    const _Float16* Kb = Kf + (size_t)b * (2048 * DIMV);
    const _Float16* Vb = Vf + (size_t)b * (2048 * DIMV);

    // Q fragments (B-operand), pre-scaled: 2 sub-blocks of 16 rows
    half8 qfrag[2][4];
#pragma unroll
    for (int sub = 0; sub < 2; sub++) {
        const size_t tq = (size_t)qg * 2 + sub;
#pragma unroll
        for (int kk = 0; kk < 4; kk++)
            qfrag[sub][kk] = *(const half8*)(Qb + ((tq * 4 + kk) * 64 + lane) * 8);
    }

    // ---- prologue: pack this lane's mask bytes into 2x u64 (bit ct*4+r) ----
    // robust: bit = (byte != 0), via OR-fold of each byte's bits into its LSB
    const unsigned char* mrow0 = mask + ((size_t)b * LQ + q0 + l16) * LK + wave * 256 + quad * 4;
    uint64_t mpack[2];
#pragma unroll
    for (int sub = 0; sub < 2; sub++) {
        uint64_t pk = 0;
#pragma unroll
        for (int ct = 0; ct < 16; ct++) {
            uint32_t w = *(const uint32_t*)(mrow0 + (size_t)sub * 16 * LK + ct * 16);
            w |= w >> 4; w |= w >> 2; w |= w >> 1;   // LSB of each byte = nonzero
            uint32_t nib = (w & 1u) | ((w >> 7) & 2u) | ((w >> 14) & 4u) | ((w >> 21) & 8u);
            pk |= (uint64_t)nib << (ct * 4);
        }
        mpack[sub] = pk;
    }

    const _Float16* kstrip = Kb + (size_t)wave * 16 * 2048; // this wave's 16 k-tiles
    const _Float16* vstrip = Vb + (size_t)wave * 16 * 2048;

    const float NEGINF = -__builtin_inff();
    float m0r = -1e30f, m1r = -1e30f;   // finite sentinel (avoid inf-inf NaN)
    float l0r = 0.f, l1r = 0.f;
    float4v oacc[2][8];
#pragma unroll
    for (int sub = 0; sub < 2; sub++)
#pragma unroll
        for (int dt = 0; dt < 8; dt++) oacc[sub][dt] = (float4v){0.f, 0.f, 0.f, 0.f};

    // ---- register double-buffer prefetch state ----
    half8 kfb[2][4], vvb[2][4];
    {   // prologue: tile 0 -> buf 0
#pragma unroll
        for (int kk = 0; kk < 4; kk++) kfb[0][kk] = *(const half8*)(kstrip + (kk * 64 + lane) * 8);
#pragma unroll
        for (int dp = 0; dp < 4; dp++) vvb[0][dp] = *(const half8*)(vstrip + (dp * 64 + lane) * 8);
    }

    // ---- pass 1: 16 tiles of 16 cols, barrier-free, issue-ahead pipeline ----
#pragma unroll 2
    for (int ct = 0; ct < 16; ++ct) {
        const int cur = ct & 1, nxt = cur ^ 1;
        const int cn  = (ct + 1) & 15;           // ct=15 reloads tile 0 (harmless)
        {   // issue next-tile loads FIRST; one full iteration of latency slack
            const _Float16* kp = kstrip + (size_t)cn * 2048;
            const _Float16* vp = vstrip + (size_t)cn * 2048;
#pragma unroll
            for (int kk = 0; kk < 4; kk++) kfb[nxt][kk] = *(const half8*)(kp + (kk * 64 + lane) * 8);
#pragma unroll
            for (int dp = 0; dp < 4; dp++) vvb[nxt][dp] = *(const half8*)(vp + (dp * 64 + lane) * 8);
        }
        __builtin_amdgcn_sched_barrier(0);       // pin: loads stay at iteration top

#pragma unroll
        for (int sub = 0; sub < 2; sub++) {
            float4v st = (float4v){0.f, 0.f, 0.f, 0.f};
            __builtin_amdgcn_s_setprio(1);
#pragma unroll
            for (int kk = 0; kk < 4; kk++)
                st = __builtin_amdgcn_mfma_f32_16x16x32_f16(kfb[cur][kk], qfrag[sub][kk], st, 0, 0, 0);
            __builtin_amdgcn_s_setprio(0);
            const uint32_t mb = (uint32_t)(mpack[sub] >> (ct * 4)) & 0xFu;  // registers, no load
            float& m = sub ? m1r : m0r;
            float& l = sub ? l1r : l0r;
            float sv[4];
#pragma unroll
            for (int r = 0; r < 4; r++) {
                float v = st[r];
                if ((mb >> r) & 1u) v = NEGINF;
                sv[r] = v;
            }
            float tmax = fmaxf(fmaxf(sv[0], sv[1]), fmaxf(sv[2], sv[3]));
            tmax = fmaxf(tmax, __shfl_xor(tmax, 16));
            tmax = fmaxf(tmax, __shfl_xor(tmax, 32));
            const bool upd = tmax > m + 3.0f;    // defer-rescale: p bounded by e^3
            if (__any(upd)) {
                const float mnew = upd ? tmax : m;
                const float sc = __expf(m - mnew);
                float scr[4];
#pragma unroll
                for (int r = 0; r < 4; r++) scr[r] = __shfl(sc, quad * 4 + r);
                l *= sc;
#pragma unroll
                for (int dt = 0; dt < 8; dt++)
#pragma unroll
                    for (int r = 0; r < 4; r++) oacc[sub][dt][r] *= scr[r];
                m = mnew;
            }
            half4v pa;
            float pp[4];
#pragma unroll
            for (int r = 0; r < 4; r++) {
                pp[r] = __expf(sv[r] - m);       // masked: exp(-inf)=0
                pa[r] = (_Float16)pp[r];
            }
            // PV first (pa is the 16x16x16 A-operand directly)
            __builtin_amdgcn_s_setprio(1);
#pragma unroll
            for (int dp = 0; dp < 4; dp++) {
                half4v vlo = __builtin_shufflevector(vvb[cur][dp], vvb[cur][dp], 0, 1, 2, 3);
                half4v vhi = __builtin_shufflevector(vvb[cur][dp], vvb[cur][dp], 4, 5, 6, 7);
                oacc[sub][2 * dp]     = __builtin_amdgcn_mfma_f32_16x16x16f16(pa, vlo, oacc[sub][2 * dp],     0, 0, 0);
                oacc[sub][2 * dp + 1] = __builtin_amdgcn_mfma_f32_16x16x16f16(pa, vhi, oacc[sub][2 * dp + 1], 0, 0, 0);
            }
            __builtin_amdgcn_s_setprio(0);
            // l-update off the critical path (feeds nothing until the merge)
            float psum = (pp[0] + pp[1]) + (pp[2] + pp[3]);
            psum += __shfl_xor(psum, 16);
            psum += __shfl_xor(psum, 32);
            l += psum;
        }
    }

    // ---- merge stats across 8 col-strips ----
    if (quad == 0) {
        redm[wave][l16]      = m0r;  redm[wave][16 + l16] = m1r;
        redl[wave][l16]      = l0r;  redl[wave][16 + l16] = l1r;
    }
    // pass-2 prologue loads issued here: latency hidden under the merge barriers
    half8 kf2[2][4];
#pragma unroll
    for (int kk = 0; kk < 4; kk++) kf2[0][kk] = *(const half8*)(kstrip + (kk * 64 + lane) * 8);
    __syncthreads();
    if (tid < 32) {
        float mm[8], ll[8];
#pragma unroll
        for (int p = 0; p < 8; p++) { mm[p] = redm[p][tid]; ll[p] = redl[p][tid]; }
        float M = mm[0];
#pragma unroll
        for (int p = 1; p < 8; p++) M = fmaxf(M, mm[p]);
        float L = 0.f;
#pragma unroll
        for (int p = 0; p < 8; p++) {
            const float e = __expf(mm[p] - M);
            swf[p][tid] = e;
            L += e * ll[p];
        }
        mcl32[tid] = M + __logf(L);
        rls32[tid] = 1.0f / L;
    }
    __syncthreads();

    // ---- PV merge: waves 0-3 -> pvsum[0], waves 4-7 -> pvsum[1], 4 rounds ----
    for (int rnd = 0; rnd < 4; ++rnd) {
        if ((wave & 3) == rnd) {
            const int bf = wave >> 2;
#pragma unroll
            for (int sub = 0; sub < 2; sub++)
#pragma unroll
                for (int r = 0; r < 4; r++) {
                    const int row = sub * 16 + quad * 4 + r;
                    const float sc = swf[wave][row];
#pragma unroll
                    for (int dt = 0; dt < 8; dt++) {
                        const float v = oacc[sub][dt][r] * sc;
                        if (rnd == 0) pvsum[bf][row][dt * 16 + l16] = v;
                        else          pvsum[bf][row][dt * 16 + l16] += v;
                    }
                }
        }
        __syncthreads();
    }

    // ---- out = (pvsum[0]+pvsum[1]) / L, coalesced float4 ----
    {
        const int row = tid >> 4;
        const int c0  = (tid & 15) * 8;
        const float rcl = rls32[row];
        float* op = out + ((size_t)b * LQ + q0 + row) * DIMV + c0;
#pragma unroll
        for (int h = 0; h < 2; h++) {
            float4v a0 = *(const float4v*)&pvsum[0][row][c0 + h * 4];
            float4v a1 = *(const float4v*)&pvsum[1][row][c0 + h * 4];
            float4v v;
#pragma unroll
            for (int j = 0; j < 4; j++) v[j] = (a0[j] + a1[j]) * rcl;
            *(float4v*)(op + h * 4) = v;
        }
    }

    // ---- pass 2: recompute QK^T (K frags L2-hot), barrier-free, prefetched ----
    const float mc0 = mcl32[l16];
    const float mc1 = mcl32[16 + l16];
    float* oa0 = out_attn + ((size_t)b * LQ + q0 + l16) * LK + wave * 256 + quad * 4;
#pragma unroll 2
    for (int ct = 0; ct < 16; ++ct) {
        const int cur = ct & 1, nxt = cur ^ 1;
        const int cn  = (ct + 1) & 15;
        {
            const _Float16* kp = kstrip + (size_t)cn * 2048;
#pragma unroll
            for (int kk = 0; kk < 4; kk++) kf2[nxt][kk] = *(const half8*)(kp + (kk * 64 + lane) * 8);
        }
        __builtin_amdgcn_sched_barrier(0);

#pragma unroll
        for (int sub = 0; sub < 2; sub++) {
            float4v st = (float4v){0.f, 0.f, 0.f, 0.f};
            __builtin_amdgcn_s_setprio(1);
#pragma unroll
            for (int kk = 0; kk < 4; kk++)
                st = __builtin_amdgcn_mfma_f32_16x16x32_f16(kf2[cur][kk], qfrag[sub][kk], st, 0, 0, 0);
            __builtin_amdgcn_s_setprio(0);
            const uint32_t mb = (uint32_t)(mpack[sub] >> (ct * 4)) & 0xFu;
            const float mc = sub ? mc1 : mc0;
            float4v o;
#pragma unroll
            for (int r = 0; r < 4; r++) {
                float lp = st[r] - mc;
                if ((mb >> r) & 1u) lp = -1.0e30f;   // masked: finite sentinel
                o[r] = fmaxf(lp, -1.0e30f);
            }
            *(float4v*)(oa0 + (size_t)sub * 16 * LK + ct * 16) = o;
        }
    }
}

extern "C" void kernel_launch(void* const* d_in, const int* in_sizes, int n_in,
                              void* d_out, int out_size, void* d_ws, size_t ws_size,
                              hipStream_t stream) {
    const float* q_f32 = (const float*)d_in[0];
    const float* c_f32 = (const float*)d_in[1];
    const unsigned char* mask = (const unsigned char*)d_in[2];

    float* out      = (float*)d_out;
    float* out_attn = out + (size_t)BB * LQ * DIMV;

    _Float16* Qf = (_Float16*)d_ws;                    // 4.19 MB each
    _Float16* Kf = Qf + (size_t)BB * LQ * DIMV;
    _Float16* Vf = Kf + (size_t)BB * LK * DIMV;

    prep_kernel<<<1536, 256, 0, stream>>>(q_f32, c_f32, Qf, Kf, Vf);
    attn_kernel<<<BB * (LQ / 32), 512, 0, stream>>>(mask, Qf, Kf, Vf, out, out_attn);
}

// Round 7
// 273.760 us; speedup vs baseline: 1.6943x; 1.0315x over previous
//
#include <hip/hip_runtime.h>
#include <cstdint>

// Problem: B=8, LQ=LK=2048, DIM=128.
// out  [B,LQ,DIM] f32 = softmax(mask? -inf : QK^T/sqrt(D)) @ K
// attn [B,LQ,LK]  f32 = log_softmax(...)  (clamp logp to -1e30)
//
// R11: R8==R10 at ~92us proved the extra waves never became resident
//      (unified VGPR+AGPR ~168/thread -> 1 block/CU). Restructure:
//      S-in-registers. Wave = 16 q-rows x 256-col strip; scores held as
//      fp16-packed s16[16] (32 VGPR). QK phase = pure MFMA stream (no
//      per-tile reduces/branches); one strip-max reduce; PV phase = pure
//      MFMA stream; NO online softmax, NO rescale, and NO pass-2 recompute
//      (logp written from held s16 after merge: -128 MFMA, -16 loads/wave).
//      Budget ~115 regs -> 4 waves/SIMD under (512,2) -> 2 blocks/CU.

#define DIMV 128
constexpr int BB = 8;
constexpr int LQ = 2048;
constexpr int LK = 2048;
constexpr float QSCALE = 0.08838834764831843f; // 1/sqrt(128), folded into Q

typedef _Float16 half8 __attribute__((ext_vector_type(8)));
typedef _Float16 half4v __attribute__((ext_vector_type(4)));
typedef float float4v __attribute__((ext_vector_type(4)));

// ---- prep: build fragment-major Qf, Kf, Vf (fp16) in ws ---- (verified R7-R10)
// Qf/Kf[b]: [tile(128)][kk(4)][lane(64)][8]  elem [t*16+l16][kk*32+quad*8+e]
// Vf[b]:    [kt(128)][dp(4)][lane(64)][8]    elem e<4:  V[kt*16+quad*4+e][(2dp)*16+l16]
//                                            elem e>=4: V[kt*16+quad*4+e-4][(2dp+1)*16+l16]
__global__ __launch_bounds__(256) void prep_kernel(const float* __restrict__ q,
                                                   const float* __restrict__ ctx,
                                                   _Float16* __restrict__ Qf,
                                                   _Float16* __restrict__ Kf,
                                                   _Float16* __restrict__ Vf) {
    __shared__ float tile[32][132];
    const int tid  = threadIdx.x;
    const int mode = blockIdx.x >> 9;     // 0:Qf 1:Kf 2:Vf
    const int t    = blockIdx.x & 511;
    const int b    = t >> 6;
    const int r0   = (t & 63) * 32;       // 32 rows of 2048
    const float4* s4 = (const float4*)((mode == 0 ? q : ctx) + ((size_t)b * 2048 + r0) * DIMV);
    for (int v = 0; v < 4; v++) {
        int off = tid + v * 256;
        float4 f = s4[off];
        int row = off >> 5, c4 = (off & 31) * 4;
        tile[row][c4 + 0] = f.x; tile[row][c4 + 1] = f.y;
        tile[row][c4 + 2] = f.z; tile[row][c4 + 3] = f.w;
    }
    __syncthreads();
    if (mode < 2) {
        const float qs = (mode == 0) ? QSCALE : 1.0f;
        _Float16* dst = (mode == 0 ? Qf : Kf) + (size_t)b * (2048 * DIMV);
        for (int c = 0; c < 2; c++) {
            int chunk = tid + c * 256;                 // (t2, kk, lane)
            int t2 = chunk >> 8, kk = (chunk >> 6) & 3, lane = chunk & 63;
            int quad = lane >> 4, l16 = lane & 15;
            int r = t2 * 16 + l16, d0 = kk * 32 + quad * 8;
            half8 h;
            for (int e = 0; e < 8; e++) h[e] = (_Float16)(tile[r][d0 + e] * qs);
            size_t tl = (size_t)(r0 >> 4) + t2;
            *(half8*)(dst + ((tl * 4 + kk) * 64 + lane) * 8) = h;
        }
    } else {
        _Float16* dst = Vf + (size_t)b * (2048 * DIMV);
        const int kt0 = r0 >> 4;
        for (int c = 0; c < 2; c++) {
            int chunk = tid + c * 256;                 // (ktl, dp, lane)
            int ktl = chunk >> 8, dp = (chunk >> 6) & 3, ln = chunk & 63;
            int qd = ln >> 4, s16i = ln & 15;
            half8 h;
            for (int e = 0; e < 4; e++) {
                h[e]     = (_Float16)tile[ktl * 16 + qd * 4 + e][(2 * dp) * 16 + s16i];
                h[e + 4] = (_Float16)tile[ktl * 16 + qd * 4 + e][(2 * dp + 1) * 16 + s16i];
            }
            *(half8*)(dst + ((((size_t)(kt0 + ktl)) * 4 + dp) * 64 + ln) * 8) = h;
        }
    }
}

// ---- main fused kernel: one block = (batch, 16 q-rows), 8 waves, 2 blk/CU ----
// wave owns col-strip [wave*256, wave*256+256) = 16 tiles.
__global__ __launch_bounds__(512, 2)
void attn_kernel(const unsigned char* __restrict__ mask,
                 const _Float16* __restrict__ Qf, const _Float16* __restrict__ Kf,
                 const _Float16* __restrict__ Vf,
                 float* __restrict__ out, float* __restrict__ out_attn) {
    __shared__ __attribute__((aligned(16))) float pvsum[2][16][132];  // 16.9 KB
    __shared__ float redm[8][16], redl[8][16], swf[8][16];
    __shared__ float mcl16[16], rls16[16];

    const int tid  = threadIdx.x;
    const int wave = tid >> 6;           // 0..7
    const int lane = tid & 63;
    const int l16  = lane & 15;
    const int quad = lane >> 4;

    const int b  = blockIdx.x & 7;       // XCD-aware: batch b -> XCD b (K+V 2MB < 4MB L2)
    const int qg = blockIdx.x >> 3;      // 0..127 (16-row q-tile)
    const int q0 = qg * 16;

    const _Float16* Qb = Qf + (size_t)b * (2048 * DIMV);
    const _Float16* Kb = Kf + (size_t)b * (2048 * DIMV);
    const _Float16* Vb = Vf + (size_t)b * (2048 * DIMV);

    // Q fragment (B-operand), pre-scaled by 1/sqrt(D)
    half8 qfrag[4];
#pragma unroll
    for (int kk = 0; kk < 4; kk++)
        qfrag[kk] = *(const half8*)(Qb + (((size_t)qg * 4 + kk) * 64 + lane) * 8);

    // ---- pack this lane's mask bytes into u64 (bit ct*4+r), QK phase only ----
    const unsigned char* mrow0 = mask + ((size_t)b * LQ + q0 + l16) * LK + wave * 256 + quad * 4;
    uint64_t mpack = 0;
#pragma unroll
    for (int ct = 0; ct < 16; ct++) {
        uint32_t w = *(const uint32_t*)(mrow0 + ct * 16);
        w |= w >> 4; w |= w >> 2; w |= w >> 1;   // LSB of each byte = nonzero
        uint32_t nib = (w & 1u) | ((w >> 7) & 2u) | ((w >> 14) & 4u) | ((w >> 21) & 8u);
        mpack |= (uint64_t)nib << (ct * 4);
    }

    const _Float16* kstrip = Kb + (size_t)wave * 16 * 2048; // this wave's 16 k-tiles
    const _Float16* vstrip = Vb + (size_t)wave * 16 * 2048;

    const float NEGINF = -__builtin_inff();

    // ---- QK phase: 16 tiles, S kept in registers as fp16 (s16: 32 VGPR) ----
    // st = S^T fragment: lane holds (k=quad*4+r, q=l16). No cross-lane ops here.
    half4v s16[16];
    float smax = -3.0e38f;
    half8 kfb[2][4];
#pragma unroll
    for (int kk = 0; kk < 4; kk++) kfb[0][kk] = *(const half8*)(kstrip + (kk * 64 + lane) * 8);

#pragma unroll
    for (int ct = 0; ct < 16; ++ct) {               // fully unrolled: s16/kfb static
        const int cur = ct & 1, nxt = cur ^ 1;
        if (ct < 15) {                               // prefetch next K tile
            const _Float16* kp = kstrip + (size_t)(ct + 1) * 2048;
#pragma unroll
            for (int kk = 0; kk < 4; kk++) kfb[nxt][kk] = *(const half8*)(kp + (kk * 64 + lane) * 8);
        }
        __builtin_amdgcn_sched_barrier(0);
        float4v st = (float4v){0.f, 0.f, 0.f, 0.f};
        __builtin_amdgcn_s_setprio(1);
#pragma unroll
        for (int kk = 0; kk < 4; kk++)
            st = __builtin_amdgcn_mfma_f32_16x16x32_f16(kfb[cur][kk], qfrag[kk], st, 0, 0, 0);
        __builtin_amdgcn_s_setprio(0);
        const uint32_t mb = (uint32_t)(mpack >> (ct * 4)) & 0xFu;
        half4v h;
        float sv[4];
#pragma unroll
        for (int r = 0; r < 4; r++) {
            float v = st[r];
            if ((mb >> r) & 1u) v = NEGINF;          // masked -> -inf (kept in s16)
            sv[r] = v;
            h[r] = (_Float16)v;
        }
        s16[ct] = h;
        smax = fmaxf(smax, fmaxf(fmaxf(sv[0], sv[1]), fmaxf(sv[2], sv[3])));
    }
    // one strip-max reduce (vs 16 per-tile reduces before)
    smax = fmaxf(smax, __shfl_xor(smax, 16));
    smax = fmaxf(smax, __shfl_xor(smax, 32));
    const float m = fmaxf(smax, -1e30f);             // finite even if strip fully masked

    // ---- PV phase: 16 tiles, dense MFMA stream; p = exp(s-m), no rescales ----
    float4v oacc[8];
#pragma unroll
    for (int dt = 0; dt < 8; dt++) oacc[dt] = (float4v){0.f, 0.f, 0.f, 0.f};
    float ps = 0.f;
    half8 vvb[2][4];
#pragma unroll
    for (int dp = 0; dp < 4; dp++) vvb[0][dp] = *(const half8*)(vstrip + (dp * 64 + lane) * 8);

#pragma unroll
    for (int ct = 0; ct < 16; ++ct) {               // fully unrolled
        const int cur = ct & 1, nxt = cur ^ 1;
        if (ct < 15) {                               // prefetch next V tile
            const _Float16* vp = vstrip + (size_t)(ct + 1) * 2048;
#pragma unroll
            for (int dp = 0; dp < 4; dp++) vvb[nxt][dp] = *(const half8*)(vp + (dp * 64 + lane) * 8);
        }
        __builtin_amdgcn_sched_barrier(0);
        half4v pa;
        float pp[4];
#pragma unroll
        for (int r = 0; r < 4; r++) {
            pp[r] = __expf((float)s16[ct][r] - m);   // masked: exp(-inf)=0
            pa[r] = (_Float16)pp[r];
        }
        __builtin_amdgcn_s_setprio(1);
#pragma unroll
        for (int dp = 0; dp < 4; dp++) {
            half4v vlo = __builtin_shufflevector(vvb[cur][dp], vvb[cur][dp], 0, 1, 2, 3);
            half4v vhi = __builtin_shufflevector(vvb[cur][dp], vvb[cur][dp], 4, 5, 6, 7);
            oacc[2 * dp]     = __builtin_amdgcn_mfma_f32_16x16x16f16(pa, vlo, oacc[2 * dp],     0, 0, 0);
            oacc[2 * dp + 1] = __builtin_amdgcn_mfma_f32_16x16x16f16(pa, vhi, oacc[2 * dp + 1], 0, 0, 0);
        }
        __builtin_amdgcn_s_setprio(0);
        ps += (pp[0] + pp[1]) + (pp[2] + pp[3]);
    }
    ps += __shfl_xor(ps, 16);
    ps += __shfl_xor(ps, 32);                        // l for this strip

    // ---- merge stats across 8 strips ----
    if (quad == 0) { redm[wave][l16] = m; redl[wave][l16] = ps; }
    __syncthreads();
    if (tid < 16) {
        float mm[8], ll[8];
#pragma unroll
        for (int p = 0; p < 8; p++) { mm[p] = redm[p][tid]; ll[p] = redl[p][tid]; }
        float M = mm[0];
#pragma unroll
        for (int p = 1; p < 8; p++) M = fmaxf(M, mm[p]);
        float L = 0.f;
#pragma unroll
        for (int p = 0; p < 8; p++) {
            const float e = __expf(mm[p] - M);
            swf[p][tid] = e;
            L += e * ll[p];
        }
        mcl16[tid] = M + __logf(L);
        rls16[tid] = 1.0f / L;
    }
    __syncthreads();

    // ---- out_attn straight from registers (pass 2 eliminated) ----
    // stores issued first: their latency overlaps the PV-merge barriers below
    {
        const float mc = mcl16[l16];
        float* oa0 = out_attn + ((size_t)b * LQ + q0 + l16) * LK + wave * 256 + quad * 4;
#pragma unroll
        for (int ct = 0; ct < 16; ++ct) {
            float4v o;
#pragma unroll
            for (int r = 0; r < 4; r++) {
                const float lp = (float)s16[ct][r] - mc;   // masked: -inf - mc = -inf
                o[r] = fmaxf(lp, -1.0e30f);                // -> finite sentinel
            }
            *(float4v*)(oa0 + ct * 16) = o;
        }
    }

    // ---- PV merge: waves 0-3 -> pvsum[0], waves 4-7 -> pvsum[1], 4 rounds ----
    for (int rnd = 0; rnd < 4; ++rnd) {
        if ((wave & 3) == rnd) {
            const int bf = wave >> 2;
#pragma unroll
            for (int r = 0; r < 4; r++) {
                const int row = quad * 4 + r;
                const float sc = swf[wave][row];
#pragma unroll
                for (int dt = 0; dt < 8; dt++) {
                    const float v = oacc[dt][r] * sc;
                    if (rnd == 0) pvsum[bf][row][dt * 16 + l16] = v;
                    else          pvsum[bf][row][dt * 16 + l16] += v;
                }
            }
        }
        __syncthreads();
    }

    // ---- out = (pvsum[0]+pvsum[1]) / L, coalesced float4 ----
    {
        const int row = tid >> 5;            // 16 rows, 32 thr/row
        const int c0  = (tid & 31) * 4;
        const float rcl = rls16[row];
        float4v a0 = *(const float4v*)&pvsum[0][row][c0];
        float4v a1 = *(const float4v*)&pvsum[1][row][c0];
        float4v v;
#pragma unroll
        for (int j = 0; j < 4; j++) v[j] = (a0[j] + a1[j]) * rcl;
        *(float4v*)(out + ((size_t)b * LQ + q0 + row) * DIMV + c0) = v;
    }
}

extern "C" void kernel_launch(void* const* d_in, const int* in_sizes, int n_in,
                              void* d_out, int out_size, void* d_ws, size_t ws_size,
                              hipStream_t stream) {
    const float* q_f32 = (const float*)d_in[0];
    const float* c_f32 = (const float*)d_in[1];
    const unsigned char* mask = (const unsigned char*)d_in[2];

    float* out      = (float*)d_out;
    float* out_attn = out + (size_t)BB * LQ * DIMV;

    _Float16* Qf = (_Float16*)d_ws;                    // 4.19 MB each
    _Float16* Kf = Qf + (size_t)BB * LQ * DIMV;
    _Float16* Vf = Kf + (size_t)BB * LK * DIMV;

    prep_kernel<<<1536, 256, 0, stream>>>(q_f32, c_f32, Qf, Kf, Vf);
    attn_kernel<<<BB * (LQ / 16), 512, 0, stream>>>(mask, Qf, Kf, Vf, out, out_attn);
}